// Round 4
// baseline (418.955 us; speedup 1.0000x reference)
//
#include <hip/hip_runtime.h>

// Problem constants
constexpr int Bn = 32, Ln = 1855, Kn = 7, Tn = 40, CIn = 8, COn = 32, TKSn = 5, TOn = 36;
constexpr int BG   = 8;               // b per (bg) group (fallback)
constexpr int KRED = Kn * TKSn * CIn; // 280
constexpr int KPAD = 288;             // padded K (9 chunks of 32), [280,288) zero
constexpr int WROW = 296;             // fallback kernel's padded wt row
constexpr int XS_ELEMS = BG * Kn * Tn * CIn;  // fallback: 17920 bf16
constexpr int XS2 = 4 * Kn * Tn * CIn;        // main: 4 b_local x 7 k x 40 t x 8 i = 8960
constexpr size_t XN = (size_t)Bn * Ln * Tn * CIn; // 18,995,200 elems

// workspace layout (bytes)
constexpr size_t WS_WT   = 0;                 // 32*288 bf16 = 18432 B
constexpr size_t WS_ZPAD = 18432;             // 128 B of zeros (masked-gather target)
constexpr size_t WS_XBF  = 18560;             // XN bf16 = 37,990,400 B
constexpr size_t WS_NEED = WS_XBF + XN * 2;

typedef __attribute__((ext_vector_type(8))) short bf16x8;          // 8 bf16 = 4 VGPRs
typedef __attribute__((ext_vector_type(8))) unsigned short u16x8;
typedef __attribute__((ext_vector_type(4))) float f32x4;           // MFMA C/D

__device__ inline unsigned short f2bf(float f) {
    unsigned u = __builtin_bit_cast(unsigned, f);
    u += 0x7fffu + ((u >> 16) & 1u); // RNE
    return (unsigned short)(u >> 16);
}

__device__ inline void gload_lds16(const void* g, void* lds) {
    __builtin_amdgcn_global_load_lds(
        (const __attribute__((address_space(1))) unsigned int*)g,
        (__attribute__((address_space(3))) unsigned int*)lds,
        16, 0, 0);
}

// ---- combined prep kernel: blocks [0,2048) convert x, block 2048 does w ----
__global__ __launch_bounds__(256) void prep_all(const float* __restrict__ x,
                                                unsigned short* __restrict__ xbf,
                                                const float* __restrict__ w,
                                                unsigned short* __restrict__ wt,
                                                unsigned short* __restrict__ zpad) {
    const int tid = threadIdx.x;
    if (blockIdx.x == 2048) {
        for (int p = tid; p < KRED * COn; p += 256) { // 8960
            int o  = p & 31;
            int kr = p >> 5;                          // (k*5+tau)*8+i
            wt[o * KPAD + kr] = f2bf(w[p]);
        }
        for (int p = tid; p < COn * (KPAD - KRED); p += 256) { // 256
            int o = p >> 3;
            wt[o * KPAD + KRED + (p & 7)] = 0;
        }
        if (tid < 64) zpad[tid] = 0; // 128 B zeros
        return;
    }
    const size_t n8 = XN / 8; // 2,374,400 groups of 8
    for (size_t p = (size_t)blockIdx.x * 256 + tid; p < n8; p += (size_t)2048 * 256) {
        float4 a = ((const float4*)x)[2 * p];
        float4 b = ((const float4*)x)[2 * p + 1];
        u16x8 v;
        v[0] = f2bf(a.x); v[1] = f2bf(a.y); v[2] = f2bf(a.z); v[3] = f2bf(a.w);
        v[4] = f2bf(b.x); v[5] = f2bf(b.y); v[6] = f2bf(b.z); v[7] = f2bf(b.w);
        *(u16x8*)&xbf[p * 8] = v;
    }
}

// ---- NT row-tiles x 32 cols; each A-read feeds 2 MFMAs (both o-halves) ----
template<int NT>
__device__ __forceinline__ void do_tiles(
    int rt0, const unsigned short* __restrict__ xs,
    const bf16x8 (&bfrag)[2][9], float bv0, float bv1,
    float* __restrict__ out, int b0, int l, int quad, int lrow)
{
    f32x4 acc[NT][2];
    int base[NT];
    #pragma unroll
    for (int i = 0; i < NT; ++i) {
        acc[i][0] = f32x4{0.f,0.f,0.f,0.f};
        acc[i][1] = f32x4{0.f,0.f,0.f,0.f};
        const int m  = (rt0 + i) * 16 + lrow;
        const int bl = m / 36, t = m - bl * 36;
        base[i] = bl * 2240 + t * 8;
    }
    __builtin_amdgcn_s_setprio(1);
    #pragma unroll
    for (int c = 0; c < 9; ++c) {
        const int p = c * 4 + quad;         // (k,tau) pair, 36th is pad
        const int knbr = p / 5, tau = p - knbr * 5;
        const int koff = knbr * 320 + tau * 8;
        #pragma unroll
        for (int i = 0; i < NT; ++i) {
            int o = base[i] + koff;
            if (c == 8 && quad == 3) o = XS2;
            bf16x8 a = *(const bf16x8*)&xs[o];
            acc[i][0] = __builtin_amdgcn_mfma_f32_16x16x32_bf16(a, bfrag[0][c], acc[i][0], 0, 0, 0);
            acc[i][1] = __builtin_amdgcn_mfma_f32_16x16x32_bf16(a, bfrag[1][c], acc[i][1], 0, 0, 0);
        }
    }
    __builtin_amdgcn_s_setprio(0);
    // epilogue: C/D layout col=lane&15, row=quad*4+reg  [m89/m91 verified]
    #pragma unroll
    for (int i = 0; i < NT; ++i) {
        #pragma unroll
        for (int reg = 0; reg < 4; ++reg) {
            const int m  = (rt0 + i) * 16 + quad * 4 + reg;
            const int bl = m / 36, t = m - bl * 36;
            const size_t off =
                (((size_t)(b0 + bl) * Ln + l) * TOn + t) * COn + lrow;
            __builtin_nontemporal_store(acc[i][0][reg] + bv0, &out[off]);
            __builtin_nontemporal_store(acc[i][1][reg] + bv1, &out[off + 16]);
        }
    }
}

// ---- main kernel: 2 waves/block share one xs tile; 4 waves/SIMD TLP ----
__global__ __launch_bounds__(128, 4) void conv_mfma5(
    const unsigned short* __restrict__ xbf,  // (B, L, T, CIn) bf16
    const int*   __restrict__ nbr,           // (L, K)
    const unsigned short* __restrict__ wt,   // [32][288] bf16
    const unsigned short* __restrict__ zpad, // 128B zeros
    const float* __restrict__ bias,          // (COn,)
    float*       __restrict__ out)           // (B, L, TOn, COn)
{
    // xs: 4 b_local x 7 k x 40 t x 8 i (bf16), +8 zero pad row at XS2.
    // 17,936 B -> 8 blocks/CU (LDS), 16 waves/CU.
    __shared__ unsigned short xs[XS2 + 8];

    const int tid  = threadIdx.x;
    const int wave = tid >> 6;
    const int lane = tid & 63;
    const int l    = blockIdx.x;
    const int b0   = blockIdx.y * 4;      // 4 batches per block

    if (tid < 8) xs[XS2 + tid] = 0;       // zero A-pad row (wave0; drained at barrier)

    // one nbr line load per wave, redistributed by shfl
    int nv = 0;
    if (lane < Kn) nv = nbr[l * Kn + lane];

    // ---- stage 18 chunks of 1024B via global->LDS; wave w takes ch ≡ w (mod 2) ----
    #pragma unroll
    for (int ch = wave; ch < 18; ch += 2) {
        if (ch < 17 || lane < 32) {
            const int u   = ch * 64 + lane;   // ushort8 unit, [0,1120)
            const int row = u / 40;           // (bl,k) row
            const int q   = u - row * 40;     // t
            const int bl  = row / 7;
            const int k   = row - bl * 7;
            const int l2  = __shfl(nv, k);
            const unsigned short* src = zpad;
            if (l2 >= 0)
                src = xbf + ((size_t)(b0 + bl) * Ln + l2) * 320 + q * 8;
            gload_lds16(src, &xs[ch * 512]);
        }
    }

    const int quad = lane >> 4;
    const int lrow = lane & 15;

    // ---- B fragments for BOTH o-halves (18 x bf16x8 = 72 VGPR), from global ----
    bf16x8 bfrag[2][9];
    #pragma unroll
    for (int oh = 0; oh < 2; ++oh)
        #pragma unroll
        for (int c = 0; c < 9; ++c)
            bfrag[oh][c] = *(const bf16x8*)(wt + (oh * 16 + lrow) * KPAD + c * 32 + quad * 8);
    const float bv0 = bias[lrow];
    const float bv1 = bias[16 + lrow];

    __syncthreads(); // vmcnt(0)+lgkmcnt(0) drain, then barrier: xs fully staged

    // ---- compute: 9 row-tiles of 16 x 32 cols, split 5/4 across the 2 waves ----
    if (wave == 0) {
        do_tiles<3>(0, xs, bfrag, bv0, bv1, out, b0, l, quad, lrow);
        do_tiles<2>(3, xs, bfrag, bv0, bv1, out, b0, l, quad, lrow);
    } else {
        do_tiles<3>(5, xs, bfrag, bv0, bv1, out, b0, l, quad, lrow);
        do_tiles<1>(8, xs, bfrag, bv0, bv1, out, b0, l, quad, lrow);
    }
}

// ---- fallback (original kernel) if workspace is too small ----
__global__ __launch_bounds__(256) void conv_mfma(
    const float* __restrict__ x, const int* __restrict__ nbr,
    const float* __restrict__ w, const float* __restrict__ bias,
    float* __restrict__ out)
{
    __shared__ unsigned short xs[XS_ELEMS + 8];
    __shared__ unsigned short wt[COn * WROW];

    const int tid = threadIdx.x;
    const int l   = blockIdx.x;
    const int bg  = blockIdx.y;

    for (int p = tid; p < KRED * COn; p += 256) {
        int o  = p & 31;
        int kr = p >> 5;
        wt[o * WROW + kr] = f2bf(w[p]);
    }
    for (int p = tid; p < COn * (WROW - KRED); p += 256) {
        int o = p >> 4;
        wt[o * WROW + KRED + (p & 15)] = 0;
    }
    if (tid < 8) xs[XS_ELEMS + tid] = 0;

    for (int p = tid; p < BG * Kn * 80; p += 256) {
        int b_local = p / 560;
        int r = p - b_local * 560;
        int k = r / 80;
        int q = r - k * 80;
        int l2 = nbr[l * Kn + k];
        float4 v = make_float4(0.f, 0.f, 0.f, 0.f);
        if (l2 >= 0)
            v = ((const float4*)x)[((size_t)(bg * BG + b_local) * Ln + l2) * 80 + q];
        ushort4 pk;
        pk.x = f2bf(v.x); pk.y = f2bf(v.y); pk.z = f2bf(v.z); pk.w = f2bf(v.w);
        *(ushort4*)&xs[p * 4] = pk;
    }
    __syncthreads();

    const int wave = tid >> 6;
    const int lane = tid & 63;
    const int quad = lane >> 4;
    const int lrow = lane & 15;
    const int o_base  = (wave & 1) * 16;
    const int rt_base = (wave >> 1) * 9;

    bf16x8 bfrag[9];
    #pragma unroll
    for (int c = 0; c < 9; ++c)
        bfrag[c] = *(const bf16x8*)&wt[(o_base + lrow) * WROW + c * 32 + quad * 8];

    const float bv = bias[o_base + lrow];

    #pragma unroll
    for (int g = 0; g < 3; ++g) {
        const int rt0 = rt_base + g * 3;
        f32x4 acc0 = {0.f,0.f,0.f,0.f}, acc1 = acc0, acc2 = acc0;
        const int m0 = (rt0 + 0) * 16 + lrow;
        const int m1 = (rt0 + 1) * 16 + lrow;
        const int m2 = (rt0 + 2) * 16 + lrow;
        const int bl0 = m0 / 36, t0 = m0 - bl0 * 36;
        const int bl1 = m1 / 36, t1 = m1 - bl1 * 36;
        const int bl2 = m2 / 36, t2 = m2 - bl2 * 36;
        const int base0 = bl0 * 2240 + t0 * 8;
        const int base1 = bl1 * 2240 + t1 * 8;
        const int base2 = bl2 * 2240 + t2 * 8;
        #pragma unroll
        for (int c = 0; c < 9; ++c) {
            const int p = c * 4 + quad;
            const int knbr = p / 5, tau = p - knbr * 5;
            const int koff = knbr * 320 + tau * 8;
            int o0 = base0 + koff, o1 = base1 + koff, o2 = base2 + koff;
            if (c == 8 && quad == 3) { o0 = XS_ELEMS; o1 = XS_ELEMS; o2 = XS_ELEMS; }
            bf16x8 a0 = *(const bf16x8*)&xs[o0];
            bf16x8 a1 = *(const bf16x8*)&xs[o1];
            bf16x8 a2 = *(const bf16x8*)&xs[o2];
            acc0 = __builtin_amdgcn_mfma_f32_16x16x32_bf16(a0, bfrag[c], acc0, 0, 0, 0);
            acc1 = __builtin_amdgcn_mfma_f32_16x16x32_bf16(a1, bfrag[c], acc1, 0, 0, 0);
            acc2 = __builtin_amdgcn_mfma_f32_16x16x32_bf16(a2, bfrag[c], acc2, 0, 0, 0);
        }
        #pragma unroll
        for (int i = 0; i < 3; ++i) {
            const f32x4 acc = (i == 0) ? acc0 : ((i == 1) ? acc1 : acc2);
            const int rt = rt0 + i;
            #pragma unroll
            for (int reg = 0; reg < 4; ++reg) {
                const int m  = rt * 16 + quad * 4 + reg;
                const int bl = m / 36, t = m - bl * 36;
                const size_t off =
                    (((size_t)(bg * BG + bl) * Ln + l) * TOn + t) * COn + o_base + lrow;
                out[off] = acc[reg] + bv;
            }
        }
    }
}

extern "C" void kernel_launch(void* const* d_in, const int* in_sizes, int n_in,
                              void* d_out, int out_size, void* d_ws, size_t ws_size,
                              hipStream_t stream) {
    const float* x    = (const float*)d_in[0];
    const int*   nbr  = (const int*)d_in[1];
    const float* w    = (const float*)d_in[2];
    const float* bias = (const float*)d_in[3];
    float*       out  = (float*)d_out;

    if (ws_size >= WS_NEED && d_ws != nullptr) {
        unsigned short* wt   = (unsigned short*)((char*)d_ws + WS_WT);
        unsigned short* zpad = (unsigned short*)((char*)d_ws + WS_ZPAD);
        unsigned short* xbf  = (unsigned short*)((char*)d_ws + WS_XBF);
        prep_all<<<2049, 256, 0, stream>>>(x, xbf, w, wt, zpad);
        // 2 waves per block: y = b-group of 4 (8 groups)
        conv_mfma5<<<dim3(Ln, 8), dim3(128), 0, stream>>>(xbf, nbr, wt, zpad, bias, out);
    } else {
        conv_mfma<<<dim3(Ln, Bn / BG), dim3(256), 0, stream>>>(x, nbr, w, bias, out);
    }
}

// Round 5
// 363.439 us; speedup vs baseline: 1.1528x; 1.1528x over previous
//
#include <hip/hip_runtime.h>

// Problem constants
constexpr int Bn = 32, Ln = 1855, Kn = 7, Tn = 40, CIn = 8, COn = 32, TKSn = 5, TOn = 36;
constexpr int BG   = 8;               // b per (bg) group (fallback)
constexpr int KRED = Kn * TKSn * CIn; // 280
constexpr int KPAD = 288;             // padded K (9 chunks of 32), [280,288) zero
constexpr int WROW = 296;             // fallback kernel's padded wt row
constexpr int XS_ELEMS = BG * Kn * Tn * CIn;  // fallback: 17920 bf16
constexpr int XB  = 2;                        // main: batches per block
constexpr int XS3 = XB * Kn * Tn * CIn;       // 2 x 7 x 40 x 8 = 4480 bf16
constexpr size_t XN = (size_t)Bn * Ln * Tn * CIn; // 18,995,200 elems

// workspace layout (bytes)
constexpr size_t WS_WT   = 0;                 // 32*288 bf16 = 18432 B
constexpr size_t WS_ZPAD = 18432;             // 128 B of zeros (masked-gather target)
constexpr size_t WS_XBF  = 18560;             // XN bf16 = 37,990,400 B
constexpr size_t WS_NEED = WS_XBF + XN * 2;

typedef __attribute__((ext_vector_type(8))) short bf16x8;          // 8 bf16 = 4 VGPRs
typedef __attribute__((ext_vector_type(8))) unsigned short u16x8;
typedef __attribute__((ext_vector_type(4))) float f32x4;           // MFMA C/D

__device__ inline unsigned short f2bf(float f) {
    unsigned u = __builtin_bit_cast(unsigned, f);
    u += 0x7fffu + ((u >> 16) & 1u); // RNE
    return (unsigned short)(u >> 16);
}

__device__ inline void gload_lds16(const void* g, void* lds) {
    __builtin_amdgcn_global_load_lds(
        (const __attribute__((address_space(1))) unsigned int*)g,
        (__attribute__((address_space(3))) unsigned int*)lds,
        16, 0, 0);
}

// ---- combined prep kernel: blocks [0,2048) convert x, block 2048 does w ----
__global__ __launch_bounds__(256) void prep_all(const float* __restrict__ x,
                                                unsigned short* __restrict__ xbf,
                                                const float* __restrict__ w,
                                                unsigned short* __restrict__ wt,
                                                unsigned short* __restrict__ zpad) {
    const int tid = threadIdx.x;
    if (blockIdx.x == 2048) {
        for (int p = tid; p < KRED * COn; p += 256) { // 8960
            int o  = p & 31;
            int kr = p >> 5;                          // (k*5+tau)*8+i
            wt[o * KPAD + kr] = f2bf(w[p]);
        }
        for (int p = tid; p < COn * (KPAD - KRED); p += 256) { // 256
            int o = p >> 3;
            wt[o * KPAD + KRED + (p & 7)] = 0;
        }
        if (tid < 64) zpad[tid] = 0; // 128 B zeros
        return;
    }
    const size_t n8 = XN / 8; // 2,374,400 groups of 8
    for (size_t p = (size_t)blockIdx.x * 256 + tid; p < n8; p += (size_t)2048 * 256) {
        float4 a = ((const float4*)x)[2 * p];
        float4 b = ((const float4*)x)[2 * p + 1];
        u16x8 v;
        v[0] = f2bf(a.x); v[1] = f2bf(a.y); v[2] = f2bf(a.z); v[3] = f2bf(a.w);
        v[4] = f2bf(b.x); v[5] = f2bf(b.y); v[6] = f2bf(b.z); v[7] = f2bf(b.w);
        *(u16x8*)&xbf[p * 8] = v;
    }
}

// ---- NT row-tiles x 32 cols; each A-read feeds 2 MFMAs (both o-halves) ----
// TAIL: the last tile is the half-tile (rows 64..71 valid). Lanes with
// lrow>=8 duplicate A-rows 64..71 (in-bounds reads); their D-rows
// (quad>=2) are garbage and masked at the store. D-row r depends only on
// A-row r, so valid rows are unaffected.
template<int RT0, int NT, bool TAIL>
__device__ __forceinline__ void do_tiles6(
    const unsigned short* __restrict__ xs,
    const bf16x8 (&bfrag)[2][9], float bv0, float bv1,
    float* __restrict__ out, int b0, int l, int quad, int lrow)
{
    f32x4 acc[NT][2];
    int base[NT];
    #pragma unroll
    for (int i = 0; i < NT; ++i) {
        acc[i][0] = f32x4{0.f,0.f,0.f,0.f};
        acc[i][1] = f32x4{0.f,0.f,0.f,0.f};
        int m;
        if (TAIL && i == NT - 1) m = 64 + (lrow & 7);   // remap invalid rows
        else                     m = (RT0 + i) * 16 + lrow;
        const int bl = m / 36, t = m - bl * 36;
        base[i] = bl * 2240 + t * 8;
    }
    __builtin_amdgcn_s_setprio(1);
    #pragma unroll
    for (int c = 0; c < 9; ++c) {
        const int p = c * 4 + quad;         // (k,tau) pair, 36th is pad
        const int knbr = p / 5, tau = p - knbr * 5;
        const int koff = knbr * 320 + tau * 8;
        #pragma unroll
        for (int i = 0; i < NT; ++i) {
            int o = base[i] + koff;
            if (c == 8 && quad == 3) o = XS3;
            bf16x8 a = *(const bf16x8*)&xs[o];
            acc[i][0] = __builtin_amdgcn_mfma_f32_16x16x32_bf16(a, bfrag[0][c], acc[i][0], 0, 0, 0);
            acc[i][1] = __builtin_amdgcn_mfma_f32_16x16x32_bf16(a, bfrag[1][c], acc[i][1], 0, 0, 0);
        }
    }
    __builtin_amdgcn_s_setprio(0);
    // epilogue: C/D layout col=lane&15, row=quad*4+reg  [m89/m91 verified]
    #pragma unroll
    for (int i = 0; i < NT; ++i) {
        const bool tail_tile = TAIL && (i == NT - 1);
        if (tail_tile && quad >= 2) continue;  // masked garbage rows (72..79)
        #pragma unroll
        for (int reg = 0; reg < 4; ++reg) {
            const int m  = (RT0 + i) * 16 + quad * 4 + reg;
            const int bl = m / 36, t = m - bl * 36;
            const size_t off =
                (((size_t)(b0 + bl) * Ln + l) * TOn + t) * COn + lrow;
            __builtin_nontemporal_store(acc[i][0][reg] + bv0, &out[off]);
            __builtin_nontemporal_store(acc[i][1][reg] + bv1, &out[off + 16]);
        }
    }
}

// ---- main kernel: 1 wave/block, 2 batches (72 rows) x 32 cols, 9KB LDS ----
__global__ __launch_bounds__(64, 3) void conv_mfma6(
    const unsigned short* __restrict__ xbf,  // (B, L, T, CIn) bf16
    const int*   __restrict__ nbr,           // (L, K)
    const unsigned short* __restrict__ wt,   // [32][288] bf16
    const unsigned short* __restrict__ zpad, // 128B zeros
    const float* __restrict__ bias,          // (COn,)
    float*       __restrict__ out)           // (B, L, TOn, COn)
{
    // xs: 2 b_local x 7 k x 40 t x 8 i (bf16), +8 zero pad row at XS3.
    // 8,976 B -> ~12 blocks/CU (VGPR-capped at 3 waves/SIMD). No barrier:
    // staged and consumed by this wave only.
    __shared__ unsigned short xs[XS3 + 8];

    const int lane = threadIdx.x;
    const int l    = blockIdx.x;
    const int b0   = blockIdx.y * XB;     // 2 batches per block

    if (lane < 8) xs[XS3 + lane] = 0;     // zero A-pad row

    // one nbr line load, redistributed by shfl
    int nv = 0;
    if (lane < Kn) nv = nbr[l * Kn + lane];

    // ---- stage 9 chunks of 1024B (last: 48 lanes) via global->LDS ----
    #pragma unroll
    for (int s = 0; s < 9; ++s) {
        if (s < 8 || lane < 48) {
            const int u   = s * 64 + lane;    // ushort8 unit, [0,560)
            const int row = u / 40;           // (bl,k) row
            const int q   = u - row * 40;     // t
            const int bl  = row / 7;
            const int k   = row - bl * 7;
            const int l2  = __shfl(nv, k);
            const unsigned short* src = zpad;
            if (l2 >= 0)
                src = xbf + ((size_t)(b0 + bl) * Ln + l2) * 320 + q * 8;
            gload_lds16(src, &xs[s * 512]);
        }
    }

    const int quad = lane >> 4;
    const int lrow = lane & 15;

    // ---- B fragments for BOTH o-halves (18 x bf16x8 = 72 VGPR), from global ----
    bf16x8 bfrag[2][9];
    #pragma unroll
    for (int oh = 0; oh < 2; ++oh)
        #pragma unroll
        for (int c = 0; c < 9; ++c)
            bfrag[oh][c] = *(const bf16x8*)(wt + (oh * 16 + lrow) * KPAD + c * 32 + quad * 8);
    const float bv0 = bias[lrow];
    const float bv1 = bias[16 + lrow];

    // Drain staging (and bfrag) before any ds_read.
    asm volatile("s_waitcnt vmcnt(0)" ::: "memory");

    // ---- compute: 4.5 row-tiles of 16 x 32 cols ----
    do_tiles6<0, 3, false>(xs, bfrag, bv0, bv1, out, b0, l, quad, lrow);
    do_tiles6<3, 2, true >(xs, bfrag, bv0, bv1, out, b0, l, quad, lrow);
}

// ---- fallback (original kernel) if workspace is too small ----
__global__ __launch_bounds__(256) void conv_mfma(
    const float* __restrict__ x, const int* __restrict__ nbr,
    const float* __restrict__ w, const float* __restrict__ bias,
    float* __restrict__ out)
{
    __shared__ unsigned short xs[XS_ELEMS + 8];
    __shared__ unsigned short wt[COn * WROW];

    const int tid = threadIdx.x;
    const int l   = blockIdx.x;
    const int bg  = blockIdx.y;

    for (int p = tid; p < KRED * COn; p += 256) {
        int o  = p & 31;
        int kr = p >> 5;
        wt[o * WROW + kr] = f2bf(w[p]);
    }
    for (int p = tid; p < COn * (WROW - KRED); p += 256) {
        int o = p >> 4;
        wt[o * WROW + KRED + (p & 15)] = 0;
    }
    if (tid < 8) xs[XS_ELEMS + tid] = 0;

    for (int p = tid; p < BG * Kn * 80; p += 256) {
        int b_local = p / 560;
        int r = p - b_local * 560;
        int k = r / 80;
        int q = r - k * 80;
        int l2 = nbr[l * Kn + k];
        float4 v = make_float4(0.f, 0.f, 0.f, 0.f);
        if (l2 >= 0)
            v = ((const float4*)x)[((size_t)(bg * BG + b_local) * Ln + l2) * 80 + q];
        ushort4 pk;
        pk.x = f2bf(v.x); pk.y = f2bf(v.y); pk.z = f2bf(v.z); pk.w = f2bf(v.w);
        *(ushort4*)&xs[p * 4] = pk;
    }
    __syncthreads();

    const int wave = tid >> 6;
    const int lane = tid & 63;
    const int quad = lane >> 4;
    const int lrow = lane & 15;
    const int o_base  = (wave & 1) * 16;
    const int rt_base = (wave >> 1) * 9;

    bf16x8 bfrag[9];
    #pragma unroll
    for (int c = 0; c < 9; ++c)
        bfrag[c] = *(const bf16x8*)&wt[(o_base + lrow) * WROW + c * 32 + quad * 8];

    const float bv = bias[o_base + lrow];

    #pragma unroll
    for (int g = 0; g < 3; ++g) {
        const int rt0 = rt_base + g * 3;
        f32x4 acc0 = {0.f,0.f,0.f,0.f}, acc1 = acc0, acc2 = acc0;
        const int m0 = (rt0 + 0) * 16 + lrow;
        const int m1 = (rt0 + 1) * 16 + lrow;
        const int m2 = (rt0 + 2) * 16 + lrow;
        const int bl0 = m0 / 36, t0 = m0 - bl0 * 36;
        const int bl1 = m1 / 36, t1 = m1 - bl1 * 36;
        const int bl2 = m2 / 36, t2 = m2 - bl2 * 36;
        const int base0 = bl0 * 2240 + t0 * 8;
        const int base1 = bl1 * 2240 + t1 * 8;
        const int base2 = bl2 * 2240 + t2 * 8;
        #pragma unroll
        for (int c = 0; c < 9; ++c) {
            const int p = c * 4 + quad;
            const int knbr = p / 5, tau = p - knbr * 5;
            const int koff = knbr * 320 + tau * 8;
            int o0 = base0 + koff, o1 = base1 + koff, o2 = base2 + koff;
            if (c == 8 && quad == 3) { o0 = XS_ELEMS; o1 = XS_ELEMS; o2 = XS_ELEMS; }
            bf16x8 a0 = *(const bf16x8*)&xs[o0];
            bf16x8 a1 = *(const bf16x8*)&xs[o1];
            bf16x8 a2 = *(const bf16x8*)&xs[o2];
            acc0 = __builtin_amdgcn_mfma_f32_16x16x32_bf16(a0, bfrag[c], acc0, 0, 0, 0);
            acc1 = __builtin_amdgcn_mfma_f32_16x16x32_bf16(a1, bfrag[c], acc1, 0, 0, 0);
            acc2 = __builtin_amdgcn_mfma_f32_16x16x32_bf16(a2, bfrag[c], acc2, 0, 0, 0);
        }
        #pragma unroll
        for (int i = 0; i < 3; ++i) {
            const f32x4 acc = (i == 0) ? acc0 : ((i == 1) ? acc1 : acc2);
            const int rt = rt0 + i;
            #pragma unroll
            for (int reg = 0; reg < 4; ++reg) {
                const int m  = rt * 16 + quad * 4 + reg;
                const int bl = m / 36, t = m - bl * 36;
                const size_t off =
                    (((size_t)(bg * BG + bl) * Ln + l) * TOn + t) * COn + o_base + lrow;
                out[off] = acc[reg] + bv;
            }
        }
    }
}

extern "C" void kernel_launch(void* const* d_in, const int* in_sizes, int n_in,
                              void* d_out, int out_size, void* d_ws, size_t ws_size,
                              hipStream_t stream) {
    const float* x    = (const float*)d_in[0];
    const int*   nbr  = (const int*)d_in[1];
    const float* w    = (const float*)d_in[2];
    const float* bias = (const float*)d_in[3];
    float*       out  = (float*)d_out;

    if (ws_size >= WS_NEED && d_ws != nullptr) {
        unsigned short* wt   = (unsigned short*)((char*)d_ws + WS_WT);
        unsigned short* zpad = (unsigned short*)((char*)d_ws + WS_ZPAD);
        unsigned short* xbf  = (unsigned short*)((char*)d_ws + WS_XBF);
        prep_all<<<2049, 256, 0, stream>>>(x, xbf, w, wt, zpad);
        // 1 wave per block, 2 batches each: y = 16 b-pairs
        conv_mfma6<<<dim3(Ln, Bn / XB), dim3(64), 0, stream>>>(xbf, nbr, wt, zpad, bias, out);
    } else {
        conv_mfma<<<dim3(Ln, Bn / BG), dim3(256), 0, stream>>>(x, nbr, w, bias, out);
    }
}